// Round 14
// baseline (211.742 us; speedup 1.0000x reference)
//
#include <hip/hip_runtime.h>
#include <hip/hip_bf16.h>
#include <math.h>

#define DPOS 768
#define ROWS 8192           // 32*256
#define NEG_INF_V (-10000.0f)
#define NSPLIT 16

// ---- k_lse geometry: 128x128 tile, 32 KB LDS, 8 waves ----
#define BM 128
#define BN 128
#define BK 64
#define CPS (ROWS / NSPLIT)   // cols per split = 512
#define NCT (CPS / BN)        // col-tiles per block = 4
#define NKC (DPOS / BK)       // K-chunks per col-tile = 12

typedef __attribute__((ext_vector_type(8))) __bf16 bf16x8;
typedef __attribute__((ext_vector_type(4))) __bf16 bf16x4;
typedef __attribute__((ext_vector_type(4))) float f32x4;

typedef const __attribute__((address_space(1))) unsigned int* gptr_t;
typedef __attribute__((address_space(3))) unsigned int* lptr_t;

// ---------------- fp32 -> bf16 conversion (two arrays per launch) ----------------
__global__ __launch_bounds__(256) void k_f2bf2(const float* __restrict__ a,
                                               const float* __restrict__ b,
                                               __bf16* __restrict__ da,
                                               __bf16* __restrict__ db, int n) {
    int i = (blockIdx.x * blockDim.x + threadIdx.x) * 4;
    const float* s = (i < n) ? a : b;
    __bf16* d = (i < n) ? da : db;
    int j = (i < n) ? i : i - n;
    float4 v = *(const float4*)(s + j);
    bf16x4 o = {(__bf16)v.x, (__bf16)v.y, (__bf16)v.z, (__bf16)v.w};
    *(bf16x4*)(d + j) = o;
}

// ---------------- LDS-staged GEMM C = A * B^T (+bias), bf16 out, 64x128 tile ------
template <int MODE>
__global__ __launch_bounds__(256, 4) void k_gemm_ld(const __bf16* __restrict__ A,
                                                    const __bf16* __restrict__ B,
                                                    const float* __restrict__ bias,
                                                    __bf16* __restrict__ outB) {
    __shared__ __align__(16) char sAB[24576];   // A[64][64]@0 (8KB), B[128][64]@8192 (16KB)

    const int tid = threadIdx.x;
    const int lane = tid & 63;
    const int wave = tid >> 6;
    const int wr = wave >> 1, wc = wave & 1;
    const int lr = lane & 15;
    const int lk = (lane >> 4) * 8;
    const int rr = (lane >> 4) * 4;
    const int row0 = blockIdx.x * 64;
    const int col0 = blockIdx.y * 128;

    int oA[2], oB[4];
    const char* As[2];
    const char* Bs[4];
#pragma unroll
    for (int c = 0; c < 2; ++c) {
        int off = tid * 16 + c * 4096;
        int row = off >> 7;                       // 0..63
        int scol = (off & 127) ^ ((row & 7) << 4);
        oA[c] = off;
        As[c] = (const char*)A + ((size_t)(row0 + row)) * (DPOS * 2) + scol;
    }
#pragma unroll
    for (int c = 0; c < 4; ++c) {
        int off = tid * 16 + c * 4096;
        int row = off >> 7;                       // 0..127
        int scol = (off & 127) ^ ((row & 7) << 4);
        oB[c] = 8192 + off;
        Bs[c] = (const char*)B + ((size_t)(col0 + row)) * (DPOS * 2) + scol;
    }

    const int sws = (lr & 7) << 4;
    const int colK0 = (lk * 2) ^ sws;
    const int colK1 = (lk * 2 + 64) ^ sws;
    const int aB0 = (wr * 32 + lr) * 128 + colK0, aB1 = (wr * 32 + lr) * 128 + colK1;
    const int bB0 = 8192 + (wc * 64 + lr) * 128 + colK0;
    const int bB1 = 8192 + (wc * 64 + lr) * 128 + colK1;

    f32x4 acc[2][4];
#pragma unroll
    for (int i = 0; i < 2; ++i)
#pragma unroll
        for (int j = 0; j < 4; ++j) acc[i][j] = (f32x4){0.f, 0.f, 0.f, 0.f};

#pragma unroll 1
    for (int kc = 0; kc < NKC; ++kc) {
        const int kb = kc * 128;
#pragma unroll
        for (int c = 0; c < 2; ++c)
            __builtin_amdgcn_global_load_lds((gptr_t)(As[c] + kb),
                                             (lptr_t)(sAB + oA[c]), 16, 0, 0);
#pragma unroll
        for (int c = 0; c < 4; ++c)
            __builtin_amdgcn_global_load_lds((gptr_t)(Bs[c] + kb),
                                             (lptr_t)(sAB + oB[c]), 16, 0, 0);
        __syncthreads();
#pragma unroll
        for (int kk = 0; kk < 2; ++kk) {
            const int aBase = kk ? aB1 : aB0;
            const int bBase = kk ? bB1 : bB0;
            bf16x8 af[2], bf_[4];
#pragma unroll
            for (int mi = 0; mi < 2; ++mi)
                af[mi] = *(const bf16x8*)(sAB + aBase + mi * 2048);
#pragma unroll
            for (int ni = 0; ni < 4; ++ni)
                bf_[ni] = *(const bf16x8*)(sAB + bBase + ni * 2048);
#pragma unroll
            for (int i = 0; i < 2; ++i)
#pragma unroll
                for (int j = 0; j < 4; ++j)
                    acc[i][j] = __builtin_amdgcn_mfma_f32_16x16x32_bf16(
                        af[i], bf_[j], acc[i][j], 0, 0, 0);
        }
        __syncthreads();
    }

#pragma unroll
    for (int j = 0; j < 4; ++j) {
        int col = col0 + wc * 64 + j * 16 + lr;
        float bv = bias[col];
#pragma unroll
        for (int i = 0; i < 2; ++i)
#pragma unroll
            for (int v = 0; v < 4; ++v) {
                int row = row0 + wr * 32 + i * 16 + rr + v;
                float val = acc[i][j][v] + bv;
                if (MODE == 0)
                    val = 0.5f * val * (1.0f + erff(val * 0.70710678118654752f));
                outB[(size_t)row * DPOS + col] = (__bf16)val;
            }
    }
}

// ---------------- LayerNorm: one WAVE per row, vectorized, no LDS/barriers --------
__global__ __launch_bounds__(256) void k_ln(const __bf16* __restrict__ h,
                                            const float* __restrict__ g,
                                            const float* __restrict__ bta,
                                            __bf16* __restrict__ out) {
    const int lane = threadIdx.x & 63;
    const int row = blockIdx.x * 4 + (threadIdx.x >> 6);
    const __bf16* hr = h + (size_t)row * DPOS;

    bf16x8 v8 = *(const bf16x8*)(hr + lane * 8);
    bf16x4 v4 = *(const bf16x4*)(hr + 512 + lane * 4);
    float f[12];
#pragma unroll
    for (int j = 0; j < 8; ++j) f[j] = (float)v8[j];
#pragma unroll
    for (int j = 0; j < 4; ++j) f[8 + j] = (float)v4[j];

    float s = 0.f, sq = 0.f;
#pragma unroll
    for (int j = 0; j < 12; ++j) { s += f[j]; sq += f[j] * f[j]; }
#pragma unroll
    for (int m = 32; m >= 1; m >>= 1) {
        s += __shfl_xor(s, m);
        sq += __shfl_xor(sq, m);
    }
    float mu = s * (1.0f / DPOS);
    float var = sq * (1.0f / DPOS) - mu * mu;
    float r = rsqrtf(var + 1e-12f);

    float4 g0 = *(const float4*)(g + lane * 8);
    float4 g1 = *(const float4*)(g + lane * 8 + 4);
    float4 g2 = *(const float4*)(g + 512 + lane * 4);
    float4 b0 = *(const float4*)(bta + lane * 8);
    float4 b1 = *(const float4*)(bta + lane * 8 + 4);
    float4 b2 = *(const float4*)(bta + 512 + lane * 4);
    float gg[12] = {g0.x, g0.y, g0.z, g0.w, g1.x, g1.y, g1.z, g1.w,
                    g2.x, g2.y, g2.z, g2.w};
    float bb[12] = {b0.x, b0.y, b0.z, b0.w, b1.x, b1.y, b1.z, b1.w,
                    b2.x, b2.y, b2.z, b2.w};

    bf16x8 o8;
    bf16x4 o4;
#pragma unroll
    for (int j = 0; j < 8; ++j) o8[j] = (__bf16)((f[j] - mu) * r * gg[j] + bb[j]);
#pragma unroll
    for (int j = 0; j < 4; ++j) o4[j] = (__bf16)((f[8 + j] - mu) * r * gg[8 + j] + bb[8 + j]);
    *(bf16x8*)(out + (size_t)row * DPOS + lane * 8) = o8;
    *(bf16x4*)(out + (size_t)row * DPOS + 512 + lane * 4) = o4;
}

// ---------------- fused logits + logsumexp + diag: 8-WAVE 128x128, 32 KB LDS ------
// R13 change: 512 thr = 8 waves (2wr x 4wc), wave tile 64x32, same 32 KB footprint
// -> up to 4 blocks x 8 waves = 32 wave slots/CU (vs 16). acc = 32 VGPR;
// __launch_bounds__(512,8) enforces <=64 VGPR for 4-block co-residency.
__global__ __launch_bounds__(512, 8) void k_lse_w8(const __bf16* __restrict__ E,
                                                   const __bf16* __restrict__ L,
                                                   const float* __restrict__ vm,
                                                   float* __restrict__ pm,
                                                   float* __restrict__ ps,
                                                   float* __restrict__ diag) {
    __shared__ __align__(16) char sAB[32768];   // A[128][64]@0, B[128][64]@16384

    const int tid = threadIdx.x;
    const int lane = tid & 63;
    const int wave = tid >> 6;
    const int wr = wave >> 2, wc = wave & 3;    // 2 x 4 waves
    const int lr = lane & 15;
    const int lk = (lane >> 4) * 8;
    const int rr = (lane >> 4) * 4;
    const int split = blockIdx.y;
    const int row0 = blockIdx.x * BM;

    float* smm = (float*)sAB;            // aliased merge scratch [4][128]
    float* sms = (float*)(sAB + 2048);   // [4][128]

    // row-mask bits: 16 rows per lane (mi 0..3, v 0..3), rows wr*64 + mi*16 + rr + v
    unsigned mrow = 0;
#pragma unroll
    for (int mi = 0; mi < 4; ++mi) {
        float4 mv = *(const float4*)(vm + row0 + wr * 64 + mi * 16 + rr);
        if (mv.x != 0.f) mrow |= 1u << (mi * 4 + 0);
        if (mv.y != 0.f) mrow |= 1u << (mi * 4 + 1);
        if (mv.z != 0.f) mrow |= 1u << (mi * 4 + 2);
        if (mv.w != 0.f) mrow |= 1u << (mi * 4 + 3);
    }

    // staging geometry: 2 x 16B per thread per operand (16 KB each, 512 threads)
    int o[2];
    const char* EsA[2];
    const char* LsB[2];
#pragma unroll
    for (int c = 0; c < 2; ++c) {
        int off = tid * 16 + c * 8192;
        int row = off >> 7;                       // 0..127
        int scol = (off & 127) ^ ((row & 7) << 4);
        o[c] = off;
        EsA[c] = (const char*)E + ((size_t)(row0 + row)) * (DPOS * 2) + scol;
        LsB[c] = (const char*)L + ((size_t)(split * CPS + row)) * (DPOS * 2) + scol;
    }

    const int sws = (lr & 7) << 4;
    const int colK0 = (lk * 2) ^ sws;
    const int colK1 = (lk * 2 + 64) ^ sws;
    const int aB0 = (wr * 64 + lr) * 128 + colK0, aB1 = (wr * 64 + lr) * 128 + colK1;
    const int bB0 = 16384 + (wc * 32 + lr) * 128 + colK0;
    const int bB1 = 16384 + (wc * 32 + lr) * 128 + colK1;

    float Mrun = -1e30f, Srun = 0.f;

#pragma unroll 1
    for (int ct = 0; ct < NCT; ++ct) {
        f32x4 acc[4][2];
#pragma unroll
        for (int i = 0; i < 4; ++i)
#pragma unroll
            for (int j = 0; j < 2; ++j) acc[i][j] = (f32x4){0.f, 0.f, 0.f, 0.f};

        const long ctb = (long)ct * BN * (DPOS * 2);

#pragma unroll 1
        for (int kc = 0; kc < NKC; ++kc) {
            const int kb = kc * (BK * 2);
#pragma unroll
            for (int c = 0; c < 2; ++c) {
                __builtin_amdgcn_global_load_lds((gptr_t)(EsA[c] + kb),
                                                 (lptr_t)(sAB + o[c]), 16, 0, 0);
                __builtin_amdgcn_global_load_lds((gptr_t)(LsB[c] + ctb + kb),
                                                 (lptr_t)(sAB + 16384 + o[c]), 16, 0, 0);
            }
            __syncthreads();
#pragma unroll
            for (int kk = 0; kk < 2; ++kk) {
                const int aBase = kk ? aB1 : aB0;
                const int bBase = kk ? bB1 : bB0;
                bf16x8 af[4], bf_[2];
#pragma unroll
                for (int mi = 0; mi < 4; ++mi)
                    af[mi] = *(const bf16x8*)(sAB + aBase + mi * 2048);
#pragma unroll
                for (int ni = 0; ni < 2; ++ni)
                    bf_[ni] = *(const bf16x8*)(sAB + bBase + ni * 2048);
#pragma unroll
                for (int i = 0; i < 4; ++i)
#pragma unroll
                    for (int j = 0; j < 2; ++j)
                        acc[i][j] = __builtin_amdgcn_mfma_f32_16x16x32_bf16(
                            af[i], bf_[j], acc[i][j], 0, 0, 0);
            }
            __syncthreads();
        }

        // ---- diagonal extraction (pre-mask, static indices) ----
        if (split * CPS + ct * BN == row0) {
#pragma unroll
            for (int mi = 0; mi < 4; ++mi)
#pragma unroll
                for (int v = 0; v < 4; ++v) {
                    int l = wr * 64 + mi * 16 + rr + v;
#pragma unroll
                    for (int ni = 0; ni < 2; ++ni)
                        if (l == wc * 32 + ni * 16 + lr)
                            diag[row0 + l] = acc[mi][ni][v];
                }
        }

        // ---- two-pass epilogue over this 128x128 logits tile ----
        float addv[2];
#pragma unroll
        for (int ni = 0; ni < 2; ++ni)
            addv[ni] = (vm[split * CPS + ct * BN + wc * 32 + ni * 16 + lr] == 0.f)
                           ? NEG_INF_V : 0.f;

        float m16[16], s16[16];
#pragma unroll
        for (int mi = 0; mi < 4; ++mi)
#pragma unroll
            for (int v = 0; v < 4; ++v) {
                const int ri = mi * 4 + v;
                bool rv = (mrow >> ri) & 1u;
                float x0 = acc[mi][0][v] + (rv ? addv[0] : 0.f);
                float x1 = acc[mi][1][v] + (rv ? addv[1] : 0.f);
                float m4 = fmaxf(x0, x1);
#pragma unroll
                for (int d = 1; d < 16; d <<= 1) m4 = fmaxf(m4, __shfl_xor(m4, d));
                float s4 = __expf(x0 - m4) + __expf(x1 - m4);
#pragma unroll
                for (int d = 1; d < 16; d <<= 1) s4 += __shfl_xor(s4, d);
                m16[ri] = m4;
                s16[ri] = s4;
            }
        if (lr == 0) {
#pragma unroll
            for (int mi = 0; mi < 4; ++mi)
#pragma unroll
                for (int v = 0; v < 4; ++v) {
                    int rl = wr * 64 + mi * 16 + rr + v;
                    smm[wc * 128 + rl] = m16[mi * 4 + v];
                    sms[wc * 128 + rl] = s16[mi * 4 + v];
                }
        }
        __syncthreads();
        if (tid < 128) {
            float m = smm[tid], s = sms[tid];
#pragma unroll
            for (int w = 1; w < 4; ++w) {
                float mo = smm[w * 128 + tid], so = sms[w * 128 + tid];
                float nm = fmaxf(m, mo);
                s = s * __expf(m - nm) + so * __expf(mo - nm);
                m = nm;
            }
            float nm2 = fmaxf(Mrun, m);
            Srun = Srun * __expf(Mrun - nm2) + s * __expf(m - nm2);
            Mrun = nm2;
        }
        __syncthreads();   // merge consumed before next ct's staging overwrites sAB
    }

    if (tid < 128) {
        size_t idx = (size_t)(row0 + tid) * NSPLIT + split;
        pm[idx] = Mrun;
        ps[idx] = Srun;
    }
}

// ---------------- loss partials: 32 blocks, one row per thread ----------------
__global__ __launch_bounds__(256) void k_loss_partial(const float* __restrict__ pm,
                                                      const float* __restrict__ ps,
                                                      const float* __restrict__ diag,
                                                      const int* __restrict__ idx,
                                                      float* __restrict__ pn,
                                                      float* __restrict__ pd) {
    const int i = blockIdx.x * 256 + threadIdx.x;   // row
    float m = pm[i * NSPLIT + 0], s = ps[i * NSPLIT + 0];
#pragma unroll
    for (int c = 1; c < NSPLIT; ++c) {
        float mo = pm[i * NSPLIT + c], so = ps[i * NSPLIT + c];
        float nm = fmaxf(m, mo);
        s = s * __expf(m - nm) + so * __expf(mo - nm);
        m = nm;
    }
    float lse = m + logf(s);
    bool valid = (idx[i] != -100);
    float accn = valid ? (diag[i] - lse) : 0.f;
    float accd = valid ? 1.f : 0.f;
#pragma unroll
    for (int d = 32; d >= 1; d >>= 1) {
        accn += __shfl_xor(accn, d);
        accd += __shfl_xor(accd, d);
    }
    __shared__ float an[4], ad[4];
    int wave = threadIdx.x >> 6, lane = threadIdx.x & 63;
    if (lane == 0) { an[wave] = accn; ad[wave] = accd; }
    __syncthreads();
    if (threadIdx.x == 0) {
        pn[blockIdx.x] = an[0] + an[1] + an[2] + an[3];
        pd[blockIdx.x] = ad[0] + ad[1] + ad[2] + ad[3];
    }
}

__global__ __launch_bounds__(64) void k_loss_final(const float* __restrict__ pn,
                                                   const float* __restrict__ pd,
                                                   float* __restrict__ out) {
    int lane = threadIdx.x;
    float n = (lane < 32) ? pn[lane] : 0.f;
    float d = (lane < 32) ? pd[lane] : 0.f;
#pragma unroll
    for (int m = 32; m >= 1; m >>= 1) {
        n += __shfl_xor(n, m);
        d += __shfl_xor(d, m);
    }
    if (lane == 0) out[0] = -n / d;
}

extern "C" void kernel_launch(void* const* d_in, const int* in_sizes, int n_in,
                              void* d_out, int out_size, void* d_ws, size_t ws_size,
                              hipStream_t stream) {
    const float* x      = (const float*)d_in[0];   // [8192][768]
    const float* labels = (const float*)d_in[1];   // [8192][768]
    const int*   lidx   = (const int*)d_in[2];     // [8192]
    const float* vm     = (const float*)d_in[3];   // [8192]
    const float* W1     = (const float*)d_in[4];   // [768][768]
    const float* b1     = (const float*)d_in[5];
    const float* ln_g   = (const float*)d_in[6];
    const float* ln_b   = (const float*)d_in[7];
    const float* Wd     = (const float*)d_in[8];
    const float* b_dec  = (const float*)d_in[9];
    float* out = (float*)d_out;

    const size_t NE = (size_t)ROWS * DPOS;       // 6291456
    const size_t NW = (size_t)DPOS * DPOS;       // 589824
    char* p = (char*)d_ws;
    __bf16* xb   = (__bf16*)p;            p += NE * 2;
    __bf16* labb = (__bf16*)p;            p += NE * 2;
    __bf16* W1b  = (__bf16*)p;            p += NW * 2;
    __bf16* Wdb  = (__bf16*)p;            p += NW * 2;
    __bf16* hb   = (__bf16*)p;            p += NE * 2;
    __bf16* hlnb = (__bf16*)p;            p += NE * 2;
    __bf16* embb = (__bf16*)p;            p += NE * 2;
    float*  pm   = (float*)p;             p += (size_t)ROWS * NSPLIT * 4;
    float*  ps   = (float*)p;             p += (size_t)ROWS * NSPLIT * 4;
    float*  diag = (float*)p;             p += (size_t)ROWS * 4;
    float*  pn   = (float*)p;             p += 32 * 4;
    float*  pd   = (float*)p;             p += 32 * 4;

    // convert fp32 -> bf16 (x+labels in one launch, W1+Wd in another)
    k_f2bf2<<<(2 * NE / 4) / 256, 256, 0, stream>>>(x, labels, xb, labb, (int)NE);
    k_f2bf2<<<(2 * NW / 4) / 256, 256, 0, stream>>>(W1, Wd, W1b, Wdb, (int)NW);

    // MFM block (LDS-staged GEMMs, 64x128 tiles -> 768 blocks)
    dim3 g1(ROWS / 64, DPOS / 128);
    k_gemm_ld<0><<<g1, 256, 0, stream>>>(xb, W1b, b1, hb);
    k_ln<<<ROWS / 4, 256, 0, stream>>>(hb, ln_g, ln_b, hlnb);
    k_gemm_ld<1><<<g1, 256, 0, stream>>>(hlnb, Wdb, b_dec, embb);

    // contrastive loss (8-wave k_lse, diag fused)
    dim3 g2(ROWS / BM, NSPLIT);
    k_lse_w8<<<g2, 512, 0, stream>>>(embb, labb, vm, pm, ps, diag);
    k_loss_partial<<<ROWS / 256, 256, 0, stream>>>(pm, ps, diag, lidx, pn, pd);
    k_loss_final<<<1, 64, 0, stream>>>(pn, pd, out);
}

// Round 15
// 209.812 us; speedup vs baseline: 1.0092x; 1.0092x over previous
//
#include <hip/hip_runtime.h>
#include <hip/hip_bf16.h>
#include <math.h>

#define DPOS 768
#define ROWS 8192           // 32*256
#define NEG_INF_V (-10000.0f)
#define NSPLIT 16

// ---- k_lse geometry: 128x128 tile, 32 KB LDS, 8 waves ----
#define BM 128
#define BN 128
#define BK 64
#define CPS (ROWS / NSPLIT)   // cols per split = 512
#define NCT (CPS / BN)        // col-tiles per block = 4
#define NKC (DPOS / BK)       // K-chunks per col-tile = 12

typedef __attribute__((ext_vector_type(8))) __bf16 bf16x8;
typedef __attribute__((ext_vector_type(4))) __bf16 bf16x4;
typedef __attribute__((ext_vector_type(4))) float f32x4;

typedef const __attribute__((address_space(1))) unsigned int* gptr_t;
typedef __attribute__((address_space(3))) unsigned int* lptr_t;

// ---------------- fp32 -> bf16 conversion (two arrays per launch) ----------------
__global__ __launch_bounds__(256) void k_f2bf2(const float* __restrict__ a,
                                               const float* __restrict__ b,
                                               __bf16* __restrict__ da,
                                               __bf16* __restrict__ db, int n) {
    int i = (blockIdx.x * blockDim.x + threadIdx.x) * 4;
    const float* s = (i < n) ? a : b;
    __bf16* d = (i < n) ? da : db;
    int j = (i < n) ? i : i - n;
    float4 v = *(const float4*)(s + j);
    bf16x4 o = {(__bf16)v.x, (__bf16)v.y, (__bf16)v.z, (__bf16)v.w};
    *(bf16x4*)(d + j) = o;
}

// ---------------- LDS-staged GEMM C = A * B^T (+bias), bf16 out, 64x128 tile ------
template <int MODE>
__global__ __launch_bounds__(256, 4) void k_gemm_ld(const __bf16* __restrict__ A,
                                                    const __bf16* __restrict__ B,
                                                    const float* __restrict__ bias,
                                                    __bf16* __restrict__ outB) {
    __shared__ __align__(16) char sAB[24576];   // A[64][64]@0 (8KB), B[128][64]@8192 (16KB)

    const int tid = threadIdx.x;
    const int lane = tid & 63;
    const int wave = tid >> 6;
    const int wr = wave >> 1, wc = wave & 1;
    const int lr = lane & 15;
    const int lk = (lane >> 4) * 8;
    const int rr = (lane >> 4) * 4;
    const int row0 = blockIdx.x * 64;
    const int col0 = blockIdx.y * 128;

    int oA[2], oB[4];
    const char* As[2];
    const char* Bs[4];
#pragma unroll
    for (int c = 0; c < 2; ++c) {
        int off = tid * 16 + c * 4096;
        int row = off >> 7;                       // 0..63
        int scol = (off & 127) ^ ((row & 7) << 4);
        oA[c] = off;
        As[c] = (const char*)A + ((size_t)(row0 + row)) * (DPOS * 2) + scol;
    }
#pragma unroll
    for (int c = 0; c < 4; ++c) {
        int off = tid * 16 + c * 4096;
        int row = off >> 7;                       // 0..127
        int scol = (off & 127) ^ ((row & 7) << 4);
        oB[c] = 8192 + off;
        Bs[c] = (const char*)B + ((size_t)(col0 + row)) * (DPOS * 2) + scol;
    }

    const int sws = (lr & 7) << 4;
    const int colK0 = (lk * 2) ^ sws;
    const int colK1 = (lk * 2 + 64) ^ sws;
    const int aB0 = (wr * 32 + lr) * 128 + colK0, aB1 = (wr * 32 + lr) * 128 + colK1;
    const int bB0 = 8192 + (wc * 64 + lr) * 128 + colK0;
    const int bB1 = 8192 + (wc * 64 + lr) * 128 + colK1;

    f32x4 acc[2][4];
#pragma unroll
    for (int i = 0; i < 2; ++i)
#pragma unroll
        for (int j = 0; j < 4; ++j) acc[i][j] = (f32x4){0.f, 0.f, 0.f, 0.f};

#pragma unroll 1
    for (int kc = 0; kc < NKC; ++kc) {
        const int kb = kc * 128;
#pragma unroll
        for (int c = 0; c < 2; ++c)
            __builtin_amdgcn_global_load_lds((gptr_t)(As[c] + kb),
                                             (lptr_t)(sAB + oA[c]), 16, 0, 0);
#pragma unroll
        for (int c = 0; c < 4; ++c)
            __builtin_amdgcn_global_load_lds((gptr_t)(Bs[c] + kb),
                                             (lptr_t)(sAB + oB[c]), 16, 0, 0);
        __syncthreads();
#pragma unroll
        for (int kk = 0; kk < 2; ++kk) {
            const int aBase = kk ? aB1 : aB0;
            const int bBase = kk ? bB1 : bB0;
            bf16x8 af[2], bf_[4];
#pragma unroll
            for (int mi = 0; mi < 2; ++mi)
                af[mi] = *(const bf16x8*)(sAB + aBase + mi * 2048);
#pragma unroll
            for (int ni = 0; ni < 4; ++ni)
                bf_[ni] = *(const bf16x8*)(sAB + bBase + ni * 2048);
#pragma unroll
            for (int i = 0; i < 2; ++i)
#pragma unroll
                for (int j = 0; j < 4; ++j)
                    acc[i][j] = __builtin_amdgcn_mfma_f32_16x16x32_bf16(
                        af[i], bf_[j], acc[i][j], 0, 0, 0);
        }
        __syncthreads();
    }

#pragma unroll
    for (int j = 0; j < 4; ++j) {
        int col = col0 + wc * 64 + j * 16 + lr;
        float bv = bias[col];
#pragma unroll
        for (int i = 0; i < 2; ++i)
#pragma unroll
            for (int v = 0; v < 4; ++v) {
                int row = row0 + wr * 32 + i * 16 + rr + v;
                float val = acc[i][j][v] + bv;
                if (MODE == 0)
                    val = 0.5f * val * (1.0f + erff(val * 0.70710678118654752f));
                outB[(size_t)row * DPOS + col] = (__bf16)val;
            }
    }
}

// ---------------- LayerNorm: one WAVE per row, vectorized, no LDS/barriers --------
__global__ __launch_bounds__(256) void k_ln(const __bf16* __restrict__ h,
                                            const float* __restrict__ g,
                                            const float* __restrict__ bta,
                                            __bf16* __restrict__ out) {
    const int lane = threadIdx.x & 63;
    const int row = blockIdx.x * 4 + (threadIdx.x >> 6);
    const __bf16* hr = h + (size_t)row * DPOS;

    bf16x8 v8 = *(const bf16x8*)(hr + lane * 8);
    bf16x4 v4 = *(const bf16x4*)(hr + 512 + lane * 4);
    float f[12];
#pragma unroll
    for (int j = 0; j < 8; ++j) f[j] = (float)v8[j];
#pragma unroll
    for (int j = 0; j < 4; ++j) f[8 + j] = (float)v4[j];

    float s = 0.f, sq = 0.f;
#pragma unroll
    for (int j = 0; j < 12; ++j) { s += f[j]; sq += f[j] * f[j]; }
#pragma unroll
    for (int m = 32; m >= 1; m >>= 1) {
        s += __shfl_xor(s, m);
        sq += __shfl_xor(sq, m);
    }
    float mu = s * (1.0f / DPOS);
    float var = sq * (1.0f / DPOS) - mu * mu;
    float r = rsqrtf(var + 1e-12f);

    float4 g0 = *(const float4*)(g + lane * 8);
    float4 g1 = *(const float4*)(g + lane * 8 + 4);
    float4 g2 = *(const float4*)(g + 512 + lane * 4);
    float4 b0 = *(const float4*)(bta + lane * 8);
    float4 b1 = *(const float4*)(bta + lane * 8 + 4);
    float4 b2 = *(const float4*)(bta + 512 + lane * 4);
    float gg[12] = {g0.x, g0.y, g0.z, g0.w, g1.x, g1.y, g1.z, g1.w,
                    g2.x, g2.y, g2.z, g2.w};
    float bb[12] = {b0.x, b0.y, b0.z, b0.w, b1.x, b1.y, b1.z, b1.w,
                    b2.x, b2.y, b2.z, b2.w};

    bf16x8 o8;
    bf16x4 o4;
#pragma unroll
    for (int j = 0; j < 8; ++j) o8[j] = (__bf16)((f[j] - mu) * r * gg[j] + bb[j]);
#pragma unroll
    for (int j = 0; j < 4; ++j) o4[j] = (__bf16)((f[8 + j] - mu) * r * gg[8 + j] + bb[8 + j]);
    *(bf16x8*)(out + (size_t)row * DPOS + lane * 8) = o8;
    *(bf16x4*)(out + (size_t)row * DPOS + 512 + lane * 4) = o4;
}

// ---------------- fused logits + logsumexp + diag: 8-WAVE 128x128, 32 KB LDS ------
// R15 change: __launch_bounds__(512, 6) -> VGPR cap ~85 (R14's (512,8) cap=32 spilled
// acc to scratch: WRITE_SIZE 101 MB). 3 blocks/CU x 8 waves = 24 waves/CU.
__global__ __launch_bounds__(512, 6) void k_lse_w8(const __bf16* __restrict__ E,
                                                   const __bf16* __restrict__ L,
                                                   const float* __restrict__ vm,
                                                   float* __restrict__ pm,
                                                   float* __restrict__ ps,
                                                   float* __restrict__ diag) {
    __shared__ __align__(16) char sAB[32768];   // A[128][64]@0, B[128][64]@16384

    const int tid = threadIdx.x;
    const int lane = tid & 63;
    const int wave = tid >> 6;
    const int wr = wave >> 2, wc = wave & 3;    // 2 x 4 waves
    const int lr = lane & 15;
    const int lk = (lane >> 4) * 8;
    const int rr = (lane >> 4) * 4;
    const int split = blockIdx.y;
    const int row0 = blockIdx.x * BM;

    float* smm = (float*)sAB;            // aliased merge scratch [4][128]
    float* sms = (float*)(sAB + 2048);   // [4][128]

    // row-mask bits: 16 rows per lane (mi 0..3, v 0..3), rows wr*64 + mi*16 + rr + v
    unsigned mrow = 0;
#pragma unroll
    for (int mi = 0; mi < 4; ++mi) {
        float4 mv = *(const float4*)(vm + row0 + wr * 64 + mi * 16 + rr);
        if (mv.x != 0.f) mrow |= 1u << (mi * 4 + 0);
        if (mv.y != 0.f) mrow |= 1u << (mi * 4 + 1);
        if (mv.z != 0.f) mrow |= 1u << (mi * 4 + 2);
        if (mv.w != 0.f) mrow |= 1u << (mi * 4 + 3);
    }

    // staging geometry: 2 x 16B per thread per operand (16 KB each, 512 threads)
    int o[2];
    const char* EsA[2];
    const char* LsB[2];
#pragma unroll
    for (int c = 0; c < 2; ++c) {
        int off = tid * 16 + c * 8192;
        int row = off >> 7;                       // 0..127
        int scol = (off & 127) ^ ((row & 7) << 4);
        o[c] = off;
        EsA[c] = (const char*)E + ((size_t)(row0 + row)) * (DPOS * 2) + scol;
        LsB[c] = (const char*)L + ((size_t)(split * CPS + row)) * (DPOS * 2) + scol;
    }

    const int sws = (lr & 7) << 4;
    const int colK0 = (lk * 2) ^ sws;
    const int colK1 = (lk * 2 + 64) ^ sws;
    const int aB0 = (wr * 64 + lr) * 128 + colK0, aB1 = (wr * 64 + lr) * 128 + colK1;
    const int bB0 = 16384 + (wc * 32 + lr) * 128 + colK0;
    const int bB1 = 16384 + (wc * 32 + lr) * 128 + colK1;

    float Mrun = -1e30f, Srun = 0.f;

#pragma unroll 1
    for (int ct = 0; ct < NCT; ++ct) {
        f32x4 acc[4][2];
#pragma unroll
        for (int i = 0; i < 4; ++i)
#pragma unroll
            for (int j = 0; j < 2; ++j) acc[i][j] = (f32x4){0.f, 0.f, 0.f, 0.f};

        const long ctb = (long)ct * BN * (DPOS * 2);

#pragma unroll 1
        for (int kc = 0; kc < NKC; ++kc) {
            const int kb = kc * (BK * 2);
#pragma unroll
            for (int c = 0; c < 2; ++c) {
                __builtin_amdgcn_global_load_lds((gptr_t)(EsA[c] + kb),
                                                 (lptr_t)(sAB + o[c]), 16, 0, 0);
                __builtin_amdgcn_global_load_lds((gptr_t)(LsB[c] + ctb + kb),
                                                 (lptr_t)(sAB + 16384 + o[c]), 16, 0, 0);
            }
            __syncthreads();
#pragma unroll
            for (int kk = 0; kk < 2; ++kk) {
                const int aBase = kk ? aB1 : aB0;
                const int bBase = kk ? bB1 : bB0;
                bf16x8 af[4], bf_[2];
#pragma unroll
                for (int mi = 0; mi < 4; ++mi)
                    af[mi] = *(const bf16x8*)(sAB + aBase + mi * 2048);
#pragma unroll
                for (int ni = 0; ni < 2; ++ni)
                    bf_[ni] = *(const bf16x8*)(sAB + bBase + ni * 2048);
#pragma unroll
                for (int i = 0; i < 4; ++i)
#pragma unroll
                    for (int j = 0; j < 2; ++j)
                        acc[i][j] = __builtin_amdgcn_mfma_f32_16x16x32_bf16(
                            af[i], bf_[j], acc[i][j], 0, 0, 0);
            }
            __syncthreads();
        }

        // ---- diagonal extraction (pre-mask, static indices) ----
        if (split * CPS + ct * BN == row0) {
#pragma unroll
            for (int mi = 0; mi < 4; ++mi)
#pragma unroll
                for (int v = 0; v < 4; ++v) {
                    int l = wr * 64 + mi * 16 + rr + v;
#pragma unroll
                    for (int ni = 0; ni < 2; ++ni)
                        if (l == wc * 32 + ni * 16 + lr)
                            diag[row0 + l] = acc[mi][ni][v];
                }
        }

        // ---- two-pass epilogue over this 128x128 logits tile ----
        float addv[2];
#pragma unroll
        for (int ni = 0; ni < 2; ++ni)
            addv[ni] = (vm[split * CPS + ct * BN + wc * 32 + ni * 16 + lr] == 0.f)
                           ? NEG_INF_V : 0.f;

        float m16[16], s16[16];
#pragma unroll
        for (int mi = 0; mi < 4; ++mi)
#pragma unroll
            for (int v = 0; v < 4; ++v) {
                const int ri = mi * 4 + v;
                bool rv = (mrow >> ri) & 1u;
                float x0 = acc[mi][0][v] + (rv ? addv[0] : 0.f);
                float x1 = acc[mi][1][v] + (rv ? addv[1] : 0.f);
                float m4 = fmaxf(x0, x1);
#pragma unroll
                for (int d = 1; d < 16; d <<= 1) m4 = fmaxf(m4, __shfl_xor(m4, d));
                float s4 = __expf(x0 - m4) + __expf(x1 - m4);
#pragma unroll
                for (int d = 1; d < 16; d <<= 1) s4 += __shfl_xor(s4, d);
                m16[ri] = m4;
                s16[ri] = s4;
            }
        if (lr == 0) {
#pragma unroll
            for (int mi = 0; mi < 4; ++mi)
#pragma unroll
                for (int v = 0; v < 4; ++v) {
                    int rl = wr * 64 + mi * 16 + rr + v;
                    smm[wc * 128 + rl] = m16[mi * 4 + v];
                    sms[wc * 128 + rl] = s16[mi * 4 + v];
                }
        }
        __syncthreads();
        if (tid < 128) {
            float m = smm[tid], s = sms[tid];
#pragma unroll
            for (int w = 1; w < 4; ++w) {
                float mo = smm[w * 128 + tid], so = sms[w * 128 + tid];
                float nm = fmaxf(m, mo);
                s = s * __expf(m - nm) + so * __expf(mo - nm);
                m = nm;
            }
            float nm2 = fmaxf(Mrun, m);
            Srun = Srun * __expf(Mrun - nm2) + s * __expf(m - nm2);
            Mrun = nm2;
        }
        __syncthreads();   // merge consumed before next ct's staging overwrites sAB
    }

    if (tid < 128) {
        size_t idx = (size_t)(row0 + tid) * NSPLIT + split;
        pm[idx] = Mrun;
        ps[idx] = Srun;
    }
}

// ---------------- loss partials: 32 blocks, one row per thread ----------------
__global__ __launch_bounds__(256) void k_loss_partial(const float* __restrict__ pm,
                                                      const float* __restrict__ ps,
                                                      const float* __restrict__ diag,
                                                      const int* __restrict__ idx,
                                                      float* __restrict__ pn,
                                                      float* __restrict__ pd) {
    const int i = blockIdx.x * 256 + threadIdx.x;   // row
    float m = pm[i * NSPLIT + 0], s = ps[i * NSPLIT + 0];
#pragma unroll
    for (int c = 1; c < NSPLIT; ++c) {
        float mo = pm[i * NSPLIT + c], so = ps[i * NSPLIT + c];
        float nm = fmaxf(m, mo);
        s = s * __expf(m - nm) + so * __expf(mo - nm);
        m = nm;
    }
    float lse = m + logf(s);
    bool valid = (idx[i] != -100);
    float accn = valid ? (diag[i] - lse) : 0.f;
    float accd = valid ? 1.f : 0.f;
#pragma unroll
    for (int d = 32; d >= 1; d >>= 1) {
        accn += __shfl_xor(accn, d);
        accd += __shfl_xor(accd, d);
    }
    __shared__ float an[4], ad[4];
    int wave = threadIdx.x >> 6, lane = threadIdx.x & 63;
    if (lane == 0) { an[wave] = accn; ad[wave] = accd; }
    __syncthreads();
    if (threadIdx.x == 0) {
        pn[blockIdx.x] = an[0] + an[1] + an[2] + an[3];
        pd[blockIdx.x] = ad[0] + ad[1] + ad[2] + ad[3];
    }
}

__global__ __launch_bounds__(64) void k_loss_final(const float* __restrict__ pn,
                                                   const float* __restrict__ pd,
                                                   float* __restrict__ out) {
    int lane = threadIdx.x;
    float n = (lane < 32) ? pn[lane] : 0.f;
    float d = (lane < 32) ? pd[lane] : 0.f;
#pragma unroll
    for (int m = 32; m >= 1; m >>= 1) {
        n += __shfl_xor(n, m);
        d += __shfl_xor(d, m);
    }
    if (lane == 0) out[0] = -n / d;
}

extern "C" void kernel_launch(void* const* d_in, const int* in_sizes, int n_in,
                              void* d_out, int out_size, void* d_ws, size_t ws_size,
                              hipStream_t stream) {
    const float* x      = (const float*)d_in[0];   // [8192][768]
    const float* labels = (const float*)d_in[1];   // [8192][768]
    const int*   lidx   = (const int*)d_in[2];     // [8192]
    const float* vm     = (const float*)d_in[3];   // [8192]
    const float* W1     = (const float*)d_in[4];   // [768][768]
    const float* b1     = (const float*)d_in[5];
    const float* ln_g   = (const float*)d_in[6];
    const float* ln_b   = (const float*)d_in[7];
    const float* Wd     = (const float*)d_in[8];
    const float* b_dec  = (const float*)d_in[9];
    float* out = (float*)d_out;

    const size_t NE = (size_t)ROWS * DPOS;       // 6291456
    const size_t NW = (size_t)DPOS * DPOS;       // 589824
    char* p = (char*)d_ws;
    __bf16* xb   = (__bf16*)p;            p += NE * 2;
    __bf16* labb = (__bf16*)p;            p += NE * 2;
    __bf16* W1b  = (__bf16*)p;            p += NW * 2;
    __bf16* Wdb  = (__bf16*)p;            p += NW * 2;
    __bf16* hb   = (__bf16*)p;            p += NE * 2;
    __bf16* hlnb = (__bf16*)p;            p += NE * 2;
    __bf16* embb = (__bf16*)p;            p += NE * 2;
    float*  pm   = (float*)p;             p += (size_t)ROWS * NSPLIT * 4;
    float*  ps   = (float*)p;             p += (size_t)ROWS * NSPLIT * 4;
    float*  diag = (float*)p;             p += (size_t)ROWS * 4;
    float*  pn   = (float*)p;             p += 32 * 4;
    float*  pd   = (float*)p;             p += 32 * 4;

    // convert fp32 -> bf16 (x+labels in one launch, W1+Wd in another)
    k_f2bf2<<<(2 * NE / 4) / 256, 256, 0, stream>>>(x, labels, xb, labb, (int)NE);
    k_f2bf2<<<(2 * NW / 4) / 256, 256, 0, stream>>>(W1, Wd, W1b, Wdb, (int)NW);

    // MFM block (LDS-staged GEMMs, 64x128 tiles -> 768 blocks)
    dim3 g1(ROWS / 64, DPOS / 128);
    k_gemm_ld<0><<<g1, 256, 0, stream>>>(xb, W1b, b1, hb);
    k_ln<<<ROWS / 4, 256, 0, stream>>>(hb, ln_g, ln_b, hlnb);
    k_gemm_ld<1><<<g1, 256, 0, stream>>>(hlnb, Wdb, b_dec, embb);

    // contrastive loss (8-wave k_lse, diag fused)
    dim3 g2(ROWS / BM, NSPLIT);
    k_lse_w8<<<g2, 512, 0, stream>>>(embb, labb, vm, pm, ps, diag);
    k_loss_partial<<<ROWS / 256, 256, 0, stream>>>(pm, ps, diag, lidx, pn, pd);
    k_loss_final<<<1, 64, 0, stream>>>(pn, pd, out);
}

// Round 16
// 178.023 us; speedup vs baseline: 1.1894x; 1.1786x over previous
//
#include <hip/hip_runtime.h>
#include <hip/hip_bf16.h>
#include <math.h>

#define DPOS 768
#define ROWS 8192           // 32*256
#define NEG_INF_V (-10000.0f)
#define NSPLIT 16

// ---- k_lse_sb3 geometry: 128x128 tile, 32 KB LDS exactly ----
#define BM 128
#define BN 128
#define BK 64
#define CPS (ROWS / NSPLIT)   // cols per split = 512
#define NCT (CPS / BN)        // col-tiles per block = 4
#define NKC (DPOS / BK)       // K-chunks per col-tile = 12

typedef __attribute__((ext_vector_type(8))) __bf16 bf16x8;
typedef __attribute__((ext_vector_type(4))) __bf16 bf16x4;
typedef __attribute__((ext_vector_type(4))) float f32x4;

typedef const __attribute__((address_space(1))) unsigned int* gptr_t;
typedef __attribute__((address_space(3))) unsigned int* lptr_t;

// ---------------- fp32 -> bf16 conversion (two arrays per launch) ----------------
__global__ __launch_bounds__(256) void k_f2bf2(const float* __restrict__ a,
                                               const float* __restrict__ b,
                                               __bf16* __restrict__ da,
                                               __bf16* __restrict__ db, int n) {
    int i = (blockIdx.x * blockDim.x + threadIdx.x) * 4;
    const float* s = (i < n) ? a : b;
    __bf16* d = (i < n) ? da : db;
    int j = (i < n) ? i : i - n;
    float4 v = *(const float4*)(s + j);
    bf16x4 o = {(__bf16)v.x, (__bf16)v.y, (__bf16)v.z, (__bf16)v.w};
    *(bf16x4*)(d + j) = o;
}

// ---------------- LDS-staged GEMM C = A * B^T (+bias), bf16 out, 64x128 tile ------
template <int MODE>
__global__ __launch_bounds__(256, 4) void k_gemm_ld(const __bf16* __restrict__ A,
                                                    const __bf16* __restrict__ B,
                                                    const float* __restrict__ bias,
                                                    __bf16* __restrict__ outB) {
    __shared__ __align__(16) char sAB[24576];   // A[64][64]@0 (8KB), B[128][64]@8192 (16KB)

    const int tid = threadIdx.x;
    const int lane = tid & 63;
    const int wave = tid >> 6;
    const int wr = wave >> 1, wc = wave & 1;
    const int lr = lane & 15;
    const int lk = (lane >> 4) * 8;
    const int rr = (lane >> 4) * 4;
    const int row0 = blockIdx.x * 64;
    const int col0 = blockIdx.y * 128;

    int oA[2], oB[4];
    const char* As[2];
    const char* Bs[4];
#pragma unroll
    for (int c = 0; c < 2; ++c) {
        int off = tid * 16 + c * 4096;
        int row = off >> 7;                       // 0..63
        int scol = (off & 127) ^ ((row & 7) << 4);
        oA[c] = off;
        As[c] = (const char*)A + ((size_t)(row0 + row)) * (DPOS * 2) + scol;
    }
#pragma unroll
    for (int c = 0; c < 4; ++c) {
        int off = tid * 16 + c * 4096;
        int row = off >> 7;                       // 0..127
        int scol = (off & 127) ^ ((row & 7) << 4);
        oB[c] = 8192 + off;
        Bs[c] = (const char*)B + ((size_t)(col0 + row)) * (DPOS * 2) + scol;
    }

    const int sws = (lr & 7) << 4;
    const int colK0 = (lk * 2) ^ sws;
    const int colK1 = (lk * 2 + 64) ^ sws;
    const int aB0 = (wr * 32 + lr) * 128 + colK0, aB1 = (wr * 32 + lr) * 128 + colK1;
    const int bB0 = 8192 + (wc * 64 + lr) * 128 + colK0;
    const int bB1 = 8192 + (wc * 64 + lr) * 128 + colK1;

    f32x4 acc[2][4];
#pragma unroll
    for (int i = 0; i < 2; ++i)
#pragma unroll
        for (int j = 0; j < 4; ++j) acc[i][j] = (f32x4){0.f, 0.f, 0.f, 0.f};

#pragma unroll 1
    for (int kc = 0; kc < NKC; ++kc) {
        const int kb = kc * 128;
#pragma unroll
        for (int c = 0; c < 2; ++c)
            __builtin_amdgcn_global_load_lds((gptr_t)(As[c] + kb),
                                             (lptr_t)(sAB + oA[c]), 16, 0, 0);
#pragma unroll
        for (int c = 0; c < 4; ++c)
            __builtin_amdgcn_global_load_lds((gptr_t)(Bs[c] + kb),
                                             (lptr_t)(sAB + oB[c]), 16, 0, 0);
        __syncthreads();
#pragma unroll
        for (int kk = 0; kk < 2; ++kk) {
            const int aBase = kk ? aB1 : aB0;
            const int bBase = kk ? bB1 : bB0;
            bf16x8 af[2], bf_[4];
#pragma unroll
            for (int mi = 0; mi < 2; ++mi)
                af[mi] = *(const bf16x8*)(sAB + aBase + mi * 2048);
#pragma unroll
            for (int ni = 0; ni < 4; ++ni)
                bf_[ni] = *(const bf16x8*)(sAB + bBase + ni * 2048);
#pragma unroll
            for (int i = 0; i < 2; ++i)
#pragma unroll
                for (int j = 0; j < 4; ++j)
                    acc[i][j] = __builtin_amdgcn_mfma_f32_16x16x32_bf16(
                        af[i], bf_[j], acc[i][j], 0, 0, 0);
        }
        __syncthreads();
    }

#pragma unroll
    for (int j = 0; j < 4; ++j) {
        int col = col0 + wc * 64 + j * 16 + lr;
        float bv = bias[col];
#pragma unroll
        for (int i = 0; i < 2; ++i)
#pragma unroll
            for (int v = 0; v < 4; ++v) {
                int row = row0 + wr * 32 + i * 16 + rr + v;
                float val = acc[i][j][v] + bv;
                if (MODE == 0)
                    val = 0.5f * val * (1.0f + erff(val * 0.70710678118654752f));
                outB[(size_t)row * DPOS + col] = (__bf16)val;
            }
    }
}

// ---------------- LayerNorm: one WAVE per row, vectorized, no LDS/barriers --------
__global__ __launch_bounds__(256) void k_ln(const __bf16* __restrict__ h,
                                            const float* __restrict__ g,
                                            const float* __restrict__ bta,
                                            __bf16* __restrict__ out) {
    const int lane = threadIdx.x & 63;
    const int row = blockIdx.x * 4 + (threadIdx.x >> 6);
    const __bf16* hr = h + (size_t)row * DPOS;

    bf16x8 v8 = *(const bf16x8*)(hr + lane * 8);
    bf16x4 v4 = *(const bf16x4*)(hr + 512 + lane * 4);
    float f[12];
#pragma unroll
    for (int j = 0; j < 8; ++j) f[j] = (float)v8[j];
#pragma unroll
    for (int j = 0; j < 4; ++j) f[8 + j] = (float)v4[j];

    float s = 0.f, sq = 0.f;
#pragma unroll
    for (int j = 0; j < 12; ++j) { s += f[j]; sq += f[j] * f[j]; }
#pragma unroll
    for (int m = 32; m >= 1; m >>= 1) {
        s += __shfl_xor(s, m);
        sq += __shfl_xor(sq, m);
    }
    float mu = s * (1.0f / DPOS);
    float var = sq * (1.0f / DPOS) - mu * mu;
    float r = rsqrtf(var + 1e-12f);

    float4 g0 = *(const float4*)(g + lane * 8);
    float4 g1 = *(const float4*)(g + lane * 8 + 4);
    float4 g2 = *(const float4*)(g + 512 + lane * 4);
    float4 b0 = *(const float4*)(bta + lane * 8);
    float4 b1 = *(const float4*)(bta + lane * 8 + 4);
    float4 b2 = *(const float4*)(bta + 512 + lane * 4);
    float gg[12] = {g0.x, g0.y, g0.z, g0.w, g1.x, g1.y, g1.z, g1.w,
                    g2.x, g2.y, g2.z, g2.w};
    float bb[12] = {b0.x, b0.y, b0.z, b0.w, b1.x, b1.y, b1.z, b1.w,
                    b2.x, b2.y, b2.z, b2.w};

    bf16x8 o8;
    bf16x4 o4;
#pragma unroll
    for (int j = 0; j < 8; ++j) o8[j] = (__bf16)((f[j] - mu) * r * gg[j] + bb[j]);
#pragma unroll
    for (int j = 0; j < 4; ++j) o4[j] = (__bf16)((f[8 + j] - mu) * r * gg[8 + j] + bb[8 + j]);
    *(bf16x8*)(out + (size_t)row * DPOS + lane * 8) = o8;
    *(bf16x4*)(out + (size_t)row * DPOS + 512 + lane * 4) = o4;
}

// ---------------- fused logits + logsumexp + diagonal extraction ----------------
// 128x128 tile in exactly 32 KB LDS, 4 waves (2x2), wave tile 64x64, 2-barrier
// chunk loop (R11/R13 structure: ~775-790 TF, 0 conflicts, occupancy ~38%,
// 4 blocks/CU via 32 KB LDS granule). NSPLIT=16.
__global__ __launch_bounds__(256, 4) void k_lse_sb3(const __bf16* __restrict__ E,
                                                    const __bf16* __restrict__ L,
                                                    const float* __restrict__ vm,
                                                    float* __restrict__ pm,
                                                    float* __restrict__ ps,
                                                    float* __restrict__ diag) {
    __shared__ __align__(16) char sAB[32768];   // A[128][64]@0, B[128][64]@16384

    const int tid = threadIdx.x;
    const int lane = tid & 63;
    const int wave = tid >> 6;
    const int wr = wave >> 1, wc = wave & 1;
    const int lr = lane & 15;
    const int lk = (lane >> 4) * 8;
    const int rr = (lane >> 4) * 4;
    const int split = blockIdx.y;
    const int row0 = blockIdx.x * BM;

    float* smm = (float*)sAB;            // aliased merge scratch [2][128]
    float* sms = (float*)(sAB + 1024);

    unsigned mrow = 0;
#pragma unroll
    for (int mi = 0; mi < 4; ++mi) {
        float4 mv = *(const float4*)(vm + row0 + wr * 64 + mi * 16 + rr);
        if (mv.x != 0.f) mrow |= 1u << (mi * 4 + 0);
        if (mv.y != 0.f) mrow |= 1u << (mi * 4 + 1);
        if (mv.z != 0.f) mrow |= 1u << (mi * 4 + 2);
        if (mv.w != 0.f) mrow |= 1u << (mi * 4 + 3);
    }

    int o[4];
    const char* EsA[4];
    const char* LsB[4];
#pragma unroll
    for (int c = 0; c < 4; ++c) {
        int off = tid * 16 + c * 4096;
        int row = off >> 7;                       // 0..127
        int scol = (off & 127) ^ ((row & 7) << 4);
        o[c] = off;
        EsA[c] = (const char*)E + ((size_t)(row0 + row)) * (DPOS * 2) + scol;
        LsB[c] = (const char*)L + ((size_t)(split * CPS + row)) * (DPOS * 2) + scol;
    }

    const int sws = (lr & 7) << 4;
    const int colK0 = (lk * 2) ^ sws;
    const int colK1 = (lk * 2 + 64) ^ sws;
    const int aB0 = (wr * 64 + lr) * 128 + colK0, aB1 = (wr * 64 + lr) * 128 + colK1;
    const int bB0 = 16384 + (wc * 64 + lr) * 128 + colK0;
    const int bB1 = 16384 + (wc * 64 + lr) * 128 + colK1;

    float Mrun = -1e30f, Srun = 0.f;

#pragma unroll 1
    for (int ct = 0; ct < NCT; ++ct) {
        f32x4 acc[4][4];
#pragma unroll
        for (int i = 0; i < 4; ++i)
#pragma unroll
            for (int j = 0; j < 4; ++j) acc[i][j] = (f32x4){0.f, 0.f, 0.f, 0.f};

        const long ctb = (long)ct * BN * (DPOS * 2);

#pragma unroll 1
        for (int kc = 0; kc < NKC; ++kc) {
            const int kb = kc * (BK * 2);
#pragma unroll
            for (int c = 0; c < 4; ++c) {
                __builtin_amdgcn_global_load_lds((gptr_t)(EsA[c] + kb),
                                                 (lptr_t)(sAB + o[c]), 16, 0, 0);
                __builtin_amdgcn_global_load_lds((gptr_t)(LsB[c] + ctb + kb),
                                                 (lptr_t)(sAB + 16384 + o[c]), 16, 0, 0);
            }
            __syncthreads();
#pragma unroll
            for (int kk = 0; kk < 2; ++kk) {
                const int aBase = kk ? aB1 : aB0;
                const int bBase = kk ? bB1 : bB0;
                bf16x8 af[4], bf_[4];
#pragma unroll
                for (int mi = 0; mi < 4; ++mi)
                    af[mi] = *(const bf16x8*)(sAB + aBase + mi * 2048);
#pragma unroll
                for (int ni = 0; ni < 4; ++ni)
                    bf_[ni] = *(const bf16x8*)(sAB + bBase + ni * 2048);
#pragma unroll
                for (int i = 0; i < 4; ++i)
#pragma unroll
                    for (int j = 0; j < 4; ++j)
                        acc[i][j] = __builtin_amdgcn_mfma_f32_16x16x32_bf16(
                            af[i], bf_[j], acc[i][j], 0, 0, 0);
            }
            __syncthreads();
        }

        // ---- diagonal extraction (pre-mask, static indices) ----
        if (split * CPS + ct * BN == row0) {
#pragma unroll
            for (int mi = 0; mi < 4; ++mi)
#pragma unroll
                for (int v = 0; v < 4; ++v) {
                    int l = wr * 64 + mi * 16 + rr + v;
#pragma unroll
                    for (int ni = 0; ni < 4; ++ni)
                        if (l == wc * 64 + ni * 16 + lr)
                            diag[row0 + l] = acc[mi][ni][v];
                }
        }

        // ---- two-pass epilogue over this 128x128 logits tile ----
        float addv[4];
#pragma unroll
        for (int ni = 0; ni < 4; ++ni)
            addv[ni] = (vm[split * CPS + ct * BN + wc * 64 + ni * 16 + lr] == 0.f)
                           ? NEG_INF_V : 0.f;

        float m16[16], s16[16];
#pragma unroll
        for (int mi = 0; mi < 4; ++mi)
#pragma unroll
            for (int v = 0; v < 4; ++v) {
                const int ri = mi * 4 + v;
                bool rv = (mrow >> ri) & 1u;
                float x0 = acc[mi][0][v] + (rv ? addv[0] : 0.f);
                float x1 = acc[mi][1][v] + (rv ? addv[1] : 0.f);
                float x2 = acc[mi][2][v] + (rv ? addv[2] : 0.f);
                float x3 = acc[mi][3][v] + (rv ? addv[3] : 0.f);
                float m4 = fmaxf(fmaxf(x0, x1), fmaxf(x2, x3));
#pragma unroll
                for (int d = 1; d < 16; d <<= 1) m4 = fmaxf(m4, __shfl_xor(m4, d));
                float s4 = __expf(x0 - m4) + __expf(x1 - m4) +
                           __expf(x2 - m4) + __expf(x3 - m4);
#pragma unroll
                for (int d = 1; d < 16; d <<= 1) s4 += __shfl_xor(s4, d);
                m16[ri] = m4;
                s16[ri] = s4;
            }
        if (lr == 0) {
#pragma unroll
            for (int mi = 0; mi < 4; ++mi)
#pragma unroll
                for (int v = 0; v < 4; ++v) {
                    int rl = wr * 64 + mi * 16 + rr + v;
                    smm[wc * 128 + rl] = m16[mi * 4 + v];
                    sms[wc * 128 + rl] = s16[mi * 4 + v];
                }
        }
        __syncthreads();
        if (tid < 128) {
            float m0 = smm[tid], s0 = sms[tid];
            float m1 = smm[128 + tid], s1 = sms[128 + tid];
            float nm = fmaxf(m0, m1);
            float s = s0 * __expf(m0 - nm) + s1 * __expf(m1 - nm);
            float nm2 = fmaxf(Mrun, nm);
            Srun = Srun * __expf(Mrun - nm2) + s * __expf(nm - nm2);
            Mrun = nm2;
        }
        __syncthreads();   // merge consumed before next ct's staging overwrites sAB
    }

    if (tid < 128) {
        size_t idx = (size_t)(row0 + tid) * NSPLIT + split;
        pm[idx] = Mrun;
        ps[idx] = Srun;
    }
}

// ---------------- loss partials: 32 blocks, one row per thread ----------------
__global__ __launch_bounds__(256) void k_loss_partial(const float* __restrict__ pm,
                                                      const float* __restrict__ ps,
                                                      const float* __restrict__ diag,
                                                      const int* __restrict__ idx,
                                                      float* __restrict__ pn,
                                                      float* __restrict__ pd) {
    const int i = blockIdx.x * 256 + threadIdx.x;   // row
    float m = pm[i * NSPLIT + 0], s = ps[i * NSPLIT + 0];
#pragma unroll
    for (int c = 1; c < NSPLIT; ++c) {
        float mo = pm[i * NSPLIT + c], so = ps[i * NSPLIT + c];
        float nm = fmaxf(m, mo);
        s = s * __expf(m - nm) + so * __expf(mo - nm);
        m = nm;
    }
    float lse = m + logf(s);
    bool valid = (idx[i] != -100);
    float accn = valid ? (diag[i] - lse) : 0.f;
    float accd = valid ? 1.f : 0.f;
#pragma unroll
    for (int d = 32; d >= 1; d >>= 1) {
        accn += __shfl_xor(accn, d);
        accd += __shfl_xor(accd, d);
    }
    __shared__ float an[4], ad[4];
    int wave = threadIdx.x >> 6, lane = threadIdx.x & 63;
    if (lane == 0) { an[wave] = accn; ad[wave] = accd; }
    __syncthreads();
    if (threadIdx.x == 0) {
        pn[blockIdx.x] = an[0] + an[1] + an[2] + an[3];
        pd[blockIdx.x] = ad[0] + ad[1] + ad[2] + ad[3];
    }
}

__global__ __launch_bounds__(64) void k_loss_final(const float* __restrict__ pn,
                                                   const float* __restrict__ pd,
                                                   float* __restrict__ out) {
    int lane = threadIdx.x;
    float n = (lane < 32) ? pn[lane] : 0.f;
    float d = (lane < 32) ? pd[lane] : 0.f;
#pragma unroll
    for (int m = 32; m >= 1; m >>= 1) {
        n += __shfl_xor(n, m);
        d += __shfl_xor(d, m);
    }
    if (lane == 0) out[0] = -n / d;
}

extern "C" void kernel_launch(void* const* d_in, const int* in_sizes, int n_in,
                              void* d_out, int out_size, void* d_ws, size_t ws_size,
                              hipStream_t stream) {
    const float* x      = (const float*)d_in[0];   // [8192][768]
    const float* labels = (const float*)d_in[1];   // [8192][768]
    const int*   lidx   = (const int*)d_in[2];     // [8192]
    const float* vm     = (const float*)d_in[3];   // [8192]
    const float* W1     = (const float*)d_in[4];   // [768][768]
    const float* b1     = (const float*)d_in[5];
    const float* ln_g   = (const float*)d_in[6];
    const float* ln_b   = (const float*)d_in[7];
    const float* Wd     = (const float*)d_in[8];
    const float* b_dec  = (const float*)d_in[9];
    float* out = (float*)d_out;

    const size_t NE = (size_t)ROWS * DPOS;       // 6291456
    const size_t NW = (size_t)DPOS * DPOS;       // 589824
    char* p = (char*)d_ws;
    __bf16* xb   = (__bf16*)p;            p += NE * 2;
    __bf16* labb = (__bf16*)p;            p += NE * 2;
    __bf16* W1b  = (__bf16*)p;            p += NW * 2;
    __bf16* Wdb  = (__bf16*)p;            p += NW * 2;
    __bf16* hb   = (__bf16*)p;            p += NE * 2;
    __bf16* hlnb = (__bf16*)p;            p += NE * 2;
    __bf16* embb = (__bf16*)p;            p += NE * 2;
    float*  pm   = (float*)p;             p += (size_t)ROWS * NSPLIT * 4;
    float*  ps   = (float*)p;             p += (size_t)ROWS * NSPLIT * 4;
    float*  diag = (float*)p;             p += (size_t)ROWS * 4;
    float*  pn   = (float*)p;             p += 32 * 4;
    float*  pd   = (float*)p;             p += 32 * 4;

    // convert fp32 -> bf16 (x+labels in one launch, W1+Wd in another)
    k_f2bf2<<<(2 * NE / 4) / 256, 256, 0, stream>>>(x, labels, xb, labb, (int)NE);
    k_f2bf2<<<(2 * NW / 4) / 256, 256, 0, stream>>>(W1, Wd, W1b, Wdb, (int)NW);

    // MFM block (LDS-staged GEMMs, 64x128 tiles -> 768 blocks)
    dim3 g1(ROWS / 64, DPOS / 128);
    k_gemm_ld<0><<<g1, 256, 0, stream>>>(xb, W1b, b1, hb);
    k_ln<<<ROWS / 4, 256, 0, stream>>>(hb, ln_g, ln_b, hlnb);
    k_gemm_ld<1><<<g1, 256, 0, stream>>>(hlnb, Wdb, b_dec, embb);

    // contrastive loss (diag extracted inside k_lse_sb3)
    dim3 g2(ROWS / BM, NSPLIT);
    k_lse_sb3<<<g2, 256, 0, stream>>>(embb, labb, vm, pm, ps, diag);
    k_loss_partial<<<ROWS / 256, 256, 0, stream>>>(pm, ps, diag, lidx, pn, pd);
    k_loss_final<<<1, 64, 0, stream>>>(pn, pd, out);
}

// Round 17
// 175.631 us; speedup vs baseline: 1.2056x; 1.0136x over previous
//
#include <hip/hip_runtime.h>
#include <hip/hip_bf16.h>
#include <math.h>

#define DPOS 768
#define ROWS 8192           // 32*256
#define NEG_INF_V (-10000.0f)
#define NSPLIT 16

// ---- k_lse_sb3 geometry: 128x128 tile, 32 KB LDS exactly ----
#define BM 128
#define BN 128
#define BK 64
#define CPS (ROWS / NSPLIT)   // cols per split = 512
#define NCT (CPS / BN)        // col-tiles per block = 4
#define NKC (DPOS / BK)       // K-chunks per col-tile = 12

typedef __attribute__((ext_vector_type(8))) __bf16 bf16x8;
typedef __attribute__((ext_vector_type(4))) __bf16 bf16x4;
typedef __attribute__((ext_vector_type(4))) float f32x4;

typedef const __attribute__((address_space(1))) unsigned int* gptr_t;
typedef __attribute__((address_space(3))) unsigned int* lptr_t;

// ---------------- fp32 -> bf16 conversion (two arrays per launch) ----------------
__global__ __launch_bounds__(256) void k_f2bf2(const float* __restrict__ a,
                                               const float* __restrict__ b,
                                               __bf16* __restrict__ da,
                                               __bf16* __restrict__ db, int n) {
    int i = (blockIdx.x * blockDim.x + threadIdx.x) * 4;
    const float* s = (i < n) ? a : b;
    __bf16* d = (i < n) ? da : db;
    int j = (i < n) ? i : i - n;
    float4 v = *(const float4*)(s + j);
    bf16x4 o = {(__bf16)v.x, (__bf16)v.y, (__bf16)v.z, (__bf16)v.w};
    *(bf16x4*)(d + j) = o;
}

// ---------------- LDS-staged GEMM C = A * B^T (+bias), bf16 out, 64x128 tile ------
// T5: setprio(1) around MFMA cluster — 3-4 independent blocks/CU give the
// wave-role diversity regime where setprio pays (m191 mechanism).
template <int MODE>
__global__ __launch_bounds__(256, 4) void k_gemm_ld(const __bf16* __restrict__ A,
                                                    const __bf16* __restrict__ B,
                                                    const float* __restrict__ bias,
                                                    __bf16* __restrict__ outB) {
    __shared__ __align__(16) char sAB[24576];   // A[64][64]@0 (8KB), B[128][64]@8192 (16KB)

    const int tid = threadIdx.x;
    const int lane = tid & 63;
    const int wave = tid >> 6;
    const int wr = wave >> 1, wc = wave & 1;
    const int lr = lane & 15;
    const int lk = (lane >> 4) * 8;
    const int rr = (lane >> 4) * 4;
    const int row0 = blockIdx.x * 64;
    const int col0 = blockIdx.y * 128;

    int oA[2], oB[4];
    const char* As[2];
    const char* Bs[4];
#pragma unroll
    for (int c = 0; c < 2; ++c) {
        int off = tid * 16 + c * 4096;
        int row = off >> 7;                       // 0..63
        int scol = (off & 127) ^ ((row & 7) << 4);
        oA[c] = off;
        As[c] = (const char*)A + ((size_t)(row0 + row)) * (DPOS * 2) + scol;
    }
#pragma unroll
    for (int c = 0; c < 4; ++c) {
        int off = tid * 16 + c * 4096;
        int row = off >> 7;                       // 0..127
        int scol = (off & 127) ^ ((row & 7) << 4);
        oB[c] = 8192 + off;
        Bs[c] = (const char*)B + ((size_t)(col0 + row)) * (DPOS * 2) + scol;
    }

    const int sws = (lr & 7) << 4;
    const int colK0 = (lk * 2) ^ sws;
    const int colK1 = (lk * 2 + 64) ^ sws;
    const int aB0 = (wr * 32 + lr) * 128 + colK0, aB1 = (wr * 32 + lr) * 128 + colK1;
    const int bB0 = 8192 + (wc * 64 + lr) * 128 + colK0;
    const int bB1 = 8192 + (wc * 64 + lr) * 128 + colK1;

    f32x4 acc[2][4];
#pragma unroll
    for (int i = 0; i < 2; ++i)
#pragma unroll
        for (int j = 0; j < 4; ++j) acc[i][j] = (f32x4){0.f, 0.f, 0.f, 0.f};

#pragma unroll 1
    for (int kc = 0; kc < NKC; ++kc) {
        const int kb = kc * 128;
#pragma unroll
        for (int c = 0; c < 2; ++c)
            __builtin_amdgcn_global_load_lds((gptr_t)(As[c] + kb),
                                             (lptr_t)(sAB + oA[c]), 16, 0, 0);
#pragma unroll
        for (int c = 0; c < 4; ++c)
            __builtin_amdgcn_global_load_lds((gptr_t)(Bs[c] + kb),
                                             (lptr_t)(sAB + oB[c]), 16, 0, 0);
        __syncthreads();
        __builtin_amdgcn_s_setprio(1);
#pragma unroll
        for (int kk = 0; kk < 2; ++kk) {
            const int aBase = kk ? aB1 : aB0;
            const int bBase = kk ? bB1 : bB0;
            bf16x8 af[2], bf_[4];
#pragma unroll
            for (int mi = 0; mi < 2; ++mi)
                af[mi] = *(const bf16x8*)(sAB + aBase + mi * 2048);
#pragma unroll
            for (int ni = 0; ni < 4; ++ni)
                bf_[ni] = *(const bf16x8*)(sAB + bBase + ni * 2048);
#pragma unroll
            for (int i = 0; i < 2; ++i)
#pragma unroll
                for (int j = 0; j < 4; ++j)
                    acc[i][j] = __builtin_amdgcn_mfma_f32_16x16x32_bf16(
                        af[i], bf_[j], acc[i][j], 0, 0, 0);
        }
        __builtin_amdgcn_s_setprio(0);
        __syncthreads();
    }

#pragma unroll
    for (int j = 0; j < 4; ++j) {
        int col = col0 + wc * 64 + j * 16 + lr;
        float bv = bias[col];
#pragma unroll
        for (int i = 0; i < 2; ++i)
#pragma unroll
            for (int v = 0; v < 4; ++v) {
                int row = row0 + wr * 32 + i * 16 + rr + v;
                float val = acc[i][j][v] + bv;
                if (MODE == 0)
                    val = 0.5f * val * (1.0f + erff(val * 0.70710678118654752f));
                outB[(size_t)row * DPOS + col] = (__bf16)val;
            }
    }
}

// ---------------- LayerNorm: one WAVE per row, vectorized, no LDS/barriers --------
__global__ __launch_bounds__(256) void k_ln(const __bf16* __restrict__ h,
                                            const float* __restrict__ g,
                                            const float* __restrict__ bta,
                                            __bf16* __restrict__ out) {
    const int lane = threadIdx.x & 63;
    const int row = blockIdx.x * 4 + (threadIdx.x >> 6);
    const __bf16* hr = h + (size_t)row * DPOS;

    bf16x8 v8 = *(const bf16x8*)(hr + lane * 8);
    bf16x4 v4 = *(const bf16x4*)(hr + 512 + lane * 4);
    float f[12];
#pragma unroll
    for (int j = 0; j < 8; ++j) f[j] = (float)v8[j];
#pragma unroll
    for (int j = 0; j < 4; ++j) f[8 + j] = (float)v4[j];

    float s = 0.f, sq = 0.f;
#pragma unroll
    for (int j = 0; j < 12; ++j) { s += f[j]; sq += f[j] * f[j]; }
#pragma unroll
    for (int m = 32; m >= 1; m >>= 1) {
        s += __shfl_xor(s, m);
        sq += __shfl_xor(sq, m);
    }
    float mu = s * (1.0f / DPOS);
    float var = sq * (1.0f / DPOS) - mu * mu;
    float r = rsqrtf(var + 1e-12f);

    float4 g0 = *(const float4*)(g + lane * 8);
    float4 g1 = *(const float4*)(g + lane * 8 + 4);
    float4 g2 = *(const float4*)(g + 512 + lane * 4);
    float4 b0 = *(const float4*)(bta + lane * 8);
    float4 b1 = *(const float4*)(bta + lane * 8 + 4);
    float4 b2 = *(const float4*)(bta + 512 + lane * 4);
    float gg[12] = {g0.x, g0.y, g0.z, g0.w, g1.x, g1.y, g1.z, g1.w,
                    g2.x, g2.y, g2.z, g2.w};
    float bb[12] = {b0.x, b0.y, b0.z, b0.w, b1.x, b1.y, b1.z, b1.w,
                    b2.x, b2.y, b2.z, b2.w};

    bf16x8 o8;
    bf16x4 o4;
#pragma unroll
    for (int j = 0; j < 8; ++j) o8[j] = (__bf16)((f[j] - mu) * r * gg[j] + bb[j]);
#pragma unroll
    for (int j = 0; j < 4; ++j) o4[j] = (__bf16)((f[8 + j] - mu) * r * gg[8 + j] + bb[8 + j]);
    *(bf16x8*)(out + (size_t)row * DPOS + lane * 8) = o8;
    *(bf16x4*)(out + (size_t)row * DPOS + 512 + lane * 4) = o4;
}

// ---------------- fused logits + logsumexp + diagonal extraction ----------------
// R13 structure + T5 setprio around MFMA cluster (4 independent blocks/CU =
// wave-role-diversity regime, m191 mechanism).
__global__ __launch_bounds__(256, 4) void k_lse_sb3(const __bf16* __restrict__ E,
                                                    const __bf16* __restrict__ L,
                                                    const float* __restrict__ vm,
                                                    float* __restrict__ pm,
                                                    float* __restrict__ ps,
                                                    float* __restrict__ diag) {
    __shared__ __align__(16) char sAB[32768];   // A[128][64]@0, B[128][64]@16384

    const int tid = threadIdx.x;
    const int lane = tid & 63;
    const int wave = tid >> 6;
    const int wr = wave >> 1, wc = wave & 1;
    const int lr = lane & 15;
    const int lk = (lane >> 4) * 8;
    const int rr = (lane >> 4) * 4;
    const int split = blockIdx.y;
    const int row0 = blockIdx.x * BM;

    float* smm = (float*)sAB;            // aliased merge scratch [2][128]
    float* sms = (float*)(sAB + 1024);

    unsigned mrow = 0;
#pragma unroll
    for (int mi = 0; mi < 4; ++mi) {
        float4 mv = *(const float4*)(vm + row0 + wr * 64 + mi * 16 + rr);
        if (mv.x != 0.f) mrow |= 1u << (mi * 4 + 0);
        if (mv.y != 0.f) mrow |= 1u << (mi * 4 + 1);
        if (mv.z != 0.f) mrow |= 1u << (mi * 4 + 2);
        if (mv.w != 0.f) mrow |= 1u << (mi * 4 + 3);
    }

    int o[4];
    const char* EsA[4];
    const char* LsB[4];
#pragma unroll
    for (int c = 0; c < 4; ++c) {
        int off = tid * 16 + c * 4096;
        int row = off >> 7;                       // 0..127
        int scol = (off & 127) ^ ((row & 7) << 4);
        o[c] = off;
        EsA[c] = (const char*)E + ((size_t)(row0 + row)) * (DPOS * 2) + scol;
        LsB[c] = (const char*)L + ((size_t)(split * CPS + row)) * (DPOS * 2) + scol;
    }

    const int sws = (lr & 7) << 4;
    const int colK0 = (lk * 2) ^ sws;
    const int colK1 = (lk * 2 + 64) ^ sws;
    const int aB0 = (wr * 64 + lr) * 128 + colK0, aB1 = (wr * 64 + lr) * 128 + colK1;
    const int bB0 = 16384 + (wc * 64 + lr) * 128 + colK0;
    const int bB1 = 16384 + (wc * 64 + lr) * 128 + colK1;

    float Mrun = -1e30f, Srun = 0.f;

#pragma unroll 1
    for (int ct = 0; ct < NCT; ++ct) {
        f32x4 acc[4][4];
#pragma unroll
        for (int i = 0; i < 4; ++i)
#pragma unroll
            for (int j = 0; j < 4; ++j) acc[i][j] = (f32x4){0.f, 0.f, 0.f, 0.f};

        const long ctb = (long)ct * BN * (DPOS * 2);

#pragma unroll 1
        for (int kc = 0; kc < NKC; ++kc) {
            const int kb = kc * (BK * 2);
#pragma unroll
            for (int c = 0; c < 4; ++c) {
                __builtin_amdgcn_global_load_lds((gptr_t)(EsA[c] + kb),
                                                 (lptr_t)(sAB + o[c]), 16, 0, 0);
                __builtin_amdgcn_global_load_lds((gptr_t)(LsB[c] + ctb + kb),
                                                 (lptr_t)(sAB + 16384 + o[c]), 16, 0, 0);
            }
            __syncthreads();
            __builtin_amdgcn_s_setprio(1);
#pragma unroll
            for (int kk = 0; kk < 2; ++kk) {
                const int aBase = kk ? aB1 : aB0;
                const int bBase = kk ? bB1 : bB0;
                bf16x8 af[4], bf_[4];
#pragma unroll
                for (int mi = 0; mi < 4; ++mi)
                    af[mi] = *(const bf16x8*)(sAB + aBase + mi * 2048);
#pragma unroll
                for (int ni = 0; ni < 4; ++ni)
                    bf_[ni] = *(const bf16x8*)(sAB + bBase + ni * 2048);
#pragma unroll
                for (int i = 0; i < 4; ++i)
#pragma unroll
                    for (int j = 0; j < 4; ++j)
                        acc[i][j] = __builtin_amdgcn_mfma_f32_16x16x32_bf16(
                            af[i], bf_[j], acc[i][j], 0, 0, 0);
            }
            __builtin_amdgcn_s_setprio(0);
            __syncthreads();
        }

        // ---- diagonal extraction (pre-mask, static indices) ----
        if (split * CPS + ct * BN == row0) {
#pragma unroll
            for (int mi = 0; mi < 4; ++mi)
#pragma unroll
                for (int v = 0; v < 4; ++v) {
                    int l = wr * 64 + mi * 16 + rr + v;
#pragma unroll
                    for (int ni = 0; ni < 4; ++ni)
                        if (l == wc * 64 + ni * 16 + lr)
                            diag[row0 + l] = acc[mi][ni][v];
                }
        }

        // ---- two-pass epilogue over this 128x128 logits tile ----
        float addv[4];
#pragma unroll
        for (int ni = 0; ni < 4; ++ni)
            addv[ni] = (vm[split * CPS + ct * BN + wc * 64 + ni * 16 + lr] == 0.f)
                           ? NEG_INF_V : 0.f;

        float m16[16], s16[16];
#pragma unroll
        for (int mi = 0; mi < 4; ++mi)
#pragma unroll
            for (int v = 0; v < 4; ++v) {
                const int ri = mi * 4 + v;
                bool rv = (mrow >> ri) & 1u;
                float x0 = acc[mi][0][v] + (rv ? addv[0] : 0.f);
                float x1 = acc[mi][1][v] + (rv ? addv[1] : 0.f);
                float x2 = acc[mi][2][v] + (rv ? addv[2] : 0.f);
                float x3 = acc[mi][3][v] + (rv ? addv[3] : 0.f);
                float m4 = fmaxf(fmaxf(x0, x1), fmaxf(x2, x3));
#pragma unroll
                for (int d = 1; d < 16; d <<= 1) m4 = fmaxf(m4, __shfl_xor(m4, d));
                float s4 = __expf(x0 - m4) + __expf(x1 - m4) +
                           __expf(x2 - m4) + __expf(x3 - m4);
#pragma unroll
                for (int d = 1; d < 16; d <<= 1) s4 += __shfl_xor(s4, d);
                m16[ri] = m4;
                s16[ri] = s4;
            }
        if (lr == 0) {
#pragma unroll
            for (int mi = 0; mi < 4; ++mi)
#pragma unroll
                for (int v = 0; v < 4; ++v) {
                    int rl = wr * 64 + mi * 16 + rr + v;
                    smm[wc * 128 + rl] = m16[mi * 4 + v];
                    sms[wc * 128 + rl] = s16[mi * 4 + v];
                }
        }
        __syncthreads();
        if (tid < 128) {
            float m0 = smm[tid], s0 = sms[tid];
            float m1 = smm[128 + tid], s1 = sms[128 + tid];
            float nm = fmaxf(m0, m1);
            float s = s0 * __expf(m0 - nm) + s1 * __expf(m1 - nm);
            float nm2 = fmaxf(Mrun, nm);
            Srun = Srun * __expf(Mrun - nm2) + s * __expf(nm - nm2);
            Mrun = nm2;
        }
        __syncthreads();   // merge consumed before next ct's staging overwrites sAB
    }

    if (tid < 128) {
        size_t idx = (size_t)(row0 + tid) * NSPLIT + split;
        pm[idx] = Mrun;
        ps[idx] = Srun;
    }
}

// ---------------- loss partials: 32 blocks, one row per thread ----------------
__global__ __launch_bounds__(256) void k_loss_partial(const float* __restrict__ pm,
                                                      const float* __restrict__ ps,
                                                      const float* __restrict__ diag,
                                                      const int* __restrict__ idx,
                                                      float* __restrict__ pn,
                                                      float* __restrict__ pd) {
    const int i = blockIdx.x * 256 + threadIdx.x;   // row
    float m = pm[i * NSPLIT + 0], s = ps[i * NSPLIT + 0];
#pragma unroll
    for (int c = 1; c < NSPLIT; ++c) {
        float mo = pm[i * NSPLIT + c], so = ps[i * NSPLIT + c];
        float nm = fmaxf(m, mo);
        s = s * __expf(m - nm) + so * __expf(mo - nm);
        m = nm;
    }
    float lse = m + logf(s);
    bool valid = (idx[i] != -100);
    float accn = valid ? (diag[i] - lse) : 0.f;
    float accd = valid ? 1.f : 0.f;
#pragma unroll
    for (int d = 32; d >= 1; d >>= 1) {
        accn += __shfl_xor(accn, d);
        accd += __shfl_xor(accd, d);
    }
    __shared__ float an[4], ad[4];
    int wave = threadIdx.x >> 6, lane = threadIdx.x & 63;
    if (lane == 0) { an[wave] = accn; ad[wave] = accd; }
    __syncthreads();
    if (threadIdx.x == 0) {
        pn[blockIdx.x] = an[0] + an[1] + an[2] + an[3];
        pd[blockIdx.x] = ad[0] + ad[1] + ad[2] + ad[3];
    }
}

__global__ __launch_bounds__(64) void k_loss_final(const float* __restrict__ pn,
                                                   const float* __restrict__ pd,
                                                   float* __restrict__ out) {
    int lane = threadIdx.x;
    float n = (lane < 32) ? pn[lane] : 0.f;
    float d = (lane < 32) ? pd[lane] : 0.f;
#pragma unroll
    for (int m = 32; m >= 1; m >>= 1) {
        n += __shfl_xor(n, m);
        d += __shfl_xor(d, m);
    }
    if (lane == 0) out[0] = -n / d;
}

extern "C" void kernel_launch(void* const* d_in, const int* in_sizes, int n_in,
                              void* d_out, int out_size, void* d_ws, size_t ws_size,
                              hipStream_t stream) {
    const float* x      = (const float*)d_in[0];   // [8192][768]
    const float* labels = (const float*)d_in[1];   // [8192][768]
    const int*   lidx   = (const int*)d_in[2];     // [8192]
    const float* vm     = (const float*)d_in[3];   // [8192]
    const float* W1     = (const float*)d_in[4];   // [768][768]
    const float* b1     = (const float*)d_in[5];
    const float* ln_g   = (const float*)d_in[6];
    const float* ln_b   = (const float*)d_in[7];
    const float* Wd     = (const float*)d_in[8];
    const float* b_dec  = (const float*)d_in[9];
    float* out = (float*)d_out;

    const size_t NE = (size_t)ROWS * DPOS;       // 6291456
    const size_t NW = (size_t)DPOS * DPOS;       // 589824
    char* p = (char*)d_ws;
    __bf16* xb   = (__bf16*)p;            p += NE * 2;
    __bf16* labb = (__bf16*)p;            p += NE * 2;
    __bf16* W1b  = (__bf16*)p;            p += NW * 2;
    __bf16* Wdb  = (__bf16*)p;            p += NW * 2;
    __bf16* hb   = (__bf16*)p;            p += NE * 2;
    __bf16* hlnb = (__bf16*)p;            p += NE * 2;
    __bf16* embb = (__bf16*)p;            p += NE * 2;
    float*  pm   = (float*)p;             p += (size_t)ROWS * NSPLIT * 4;
    float*  ps   = (float*)p;             p += (size_t)ROWS * NSPLIT * 4;
    float*  diag = (float*)p;             p += (size_t)ROWS * 4;
    float*  pn   = (float*)p;             p += 32 * 4;
    float*  pd   = (float*)p;             p += 32 * 4;

    // convert fp32 -> bf16 (x+labels in one launch, W1+Wd in another)
    k_f2bf2<<<(2 * NE / 4) / 256, 256, 0, stream>>>(x, labels, xb, labb, (int)NE);
    k_f2bf2<<<(2 * NW / 4) / 256, 256, 0, stream>>>(W1, Wd, W1b, Wdb, (int)NW);

    // MFM block (LDS-staged GEMMs, 64x128 tiles -> 768 blocks)
    dim3 g1(ROWS / 64, DPOS / 128);
    k_gemm_ld<0><<<g1, 256, 0, stream>>>(xb, W1b, b1, hb);
    k_ln<<<ROWS / 4, 256, 0, stream>>>(hb, ln_g, ln_b, hlnb);
    k_gemm_ld<1><<<g1, 256, 0, stream>>>(hlnb, Wdb, b_dec, embb);

    // contrastive loss (diag extracted inside k_lse_sb3)
    dim3 g2(ROWS / BM, NSPLIT);
    k_lse_sb3<<<g2, 256, 0, stream>>>(embb, labb, vm, pm, ps, diag);
    k_loss_partial<<<ROWS / 256, 256, 0, stream>>>(pm, ps, diag, lidx, pn, pd);
    k_loss_final<<<1, 64, 0, stream>>>(pn, pd, out);
}